// Round 1
// baseline (490.356 us; speedup 1.0000x reference)
//
#include <hip/hip_runtime.h>
#include <hip/hip_bf16.h>

// Effi_MVS: B=1, V=5, C=32, D=48, H=128, W=160, RATIO=8.
// Round 4: k_warpvar was VMEM-instruction-bound (~1000 VMEM instrs/wave at
// ~6 cyc each == the whole 153 us; HBM only 5.8%, VALU 62%).
//   Fix A: transpose features to [v][HW][32] (c-contiguous) so every bilinear
//          tap is a float4 over 4 channels -> 544 scalar loads/thread -> <=136
//          vector loads; tap base addresses computed once per thread.
//   Fix B: this problem's homographies have gy == y exactly (rot=I, trans=
//          (400v,0,0)), so wy==0 and the two y+1 corners have weight 0 but
//          were still loaded. Runtime-detected 2-tap path halves taps (general
//          inputs with wy!=0 fall back to the 4-tap path).
// featT aliases the pre buffer region (featT dead before k_conv writes pre).

#define NV 5
#define NC 32
#define ND 48
#define NH 128
#define NW 160
#define HW (NH * NW)
#define DHW (ND * HW)

typedef __attribute__((ext_vector_type(2))) float f32x2;
typedef __attribute__((ext_vector_type(4))) float f32x4;

// ws layout (bytes)
#define OFF_M      0          // float M[4][12]
#define OFF_WF     256        // float wf[32][28]
#define OFF_DEPTHF 4096       // float depthf[20480]            (end 86,016)
#define OFF_FEATT  86016      // float featT[5][HW][32] = 13,107,200
#define OFF_PRE    86016      // float pre[48*128*160] ALIASES featT (3.9MB < 13.1MB)
#define OFF_WV     13193216   // bf16 WV[27][48*128*160] = 53,084,160
// total = 66,277,376 bytes

// ---------------------------------------------------------------- K1: setup
__global__ void k_setup(const float* __restrict__ proj,
                        const float* __restrict__ wreg,
                        float* __restrict__ M, float* __restrict__ wf) {
  if (threadIdx.x != 0) return;
  double P[NV][2][4][4];
  for (int v = 0; v < NV; ++v)
    for (int m = 0; m < 2; ++m)
      for (int i = 0; i < 4; ++i)
        for (int j = 0; j < 4; ++j)
          P[v][m][i][j] = (double)proj[((v * 2 + m) * 4 + i) * 4 + j];
  double C[NV][4][4];
  for (int v = 0; v < NV; ++v) {
    for (int i = 0; i < 4; ++i)
      for (int j = 0; j < 4; ++j) C[v][i][j] = P[v][0][i][j];
    for (int i = 0; i < 3; ++i)
      for (int j = 0; j < 4; ++j) {
        double s = 0.0;
        for (int k = 0; k < 3; ++k) s += P[v][1][i][k] * P[v][0][k][j];
        C[v][i][j] = s;
      }
  }
  double a[4][8];
  for (int i = 0; i < 4; ++i)
    for (int j = 0; j < 4; ++j) { a[i][j] = C[0][i][j]; a[i][j + 4] = (i == j) ? 1.0 : 0.0; }
  for (int col = 0; col < 4; ++col) {
    int piv = col; double best = fabs(a[col][col]);
    for (int r = col + 1; r < 4; ++r) { double v = fabs(a[r][col]); if (v > best) { best = v; piv = r; } }
    if (piv != col)
      for (int j = 0; j < 8; ++j) { double t = a[col][j]; a[col][j] = a[piv][j]; a[piv][j] = t; }
    double pv = a[col][col];
    for (int j = 0; j < 8; ++j) a[col][j] /= pv;
    for (int r = 0; r < 4; ++r) if (r != col) {
      double f = a[r][col];
      for (int j = 0; j < 8; ++j) a[r][j] -= f * a[col][j];
    }
  }
  double inv[4][4];
  for (int i = 0; i < 4; ++i)
    for (int j = 0; j < 4; ++j) inv[i][j] = a[i][j + 4];
  for (int v = 1; v < NV; ++v) {
    float* m = M + (v - 1) * 12;
    for (int i = 0; i < 3; ++i) {
      double r[4] = {0, 0, 0, 0};
      for (int k = 0; k < 4; ++k) {
        double cv = C[v][i][k];
        for (int j = 0; j < 4; ++j) r[j] += cv * inv[k][j];
      }
      m[i * 3 + 0] = (float)r[0]; m[i * 3 + 1] = (float)r[1]; m[i * 3 + 2] = (float)r[2];
      m[9 + i] = (float)r[3];
    }
  }
  for (int c = 0; c < NC; ++c) {
    for (int t = 0; t < 27; ++t) wf[c * 28 + t] = wreg[c * 27 + t];
    wf[c * 28 + 27] = 0.f;
  }
}

// --------------------------------------------- K1b: feature transpose to HWC
__global__ __launch_bounds__(256) void k_transpose(const float* __restrict__ feat,
                                                   float* __restrict__ featT) {
  int t = blockIdx.x * 256 + threadIdx.x;   // [0, 5*HW)
  int v = t / HW;
  int pix = t - v * HW;
  float r[NC];
#pragma unroll
  for (int c = 0; c < NC; ++c) r[c] = feat[(v * NC + c) * HW + pix];
  f32x4* dst = (f32x4*)(featT + (size_t)t * NC);   // (v*HW+pix) == t
#pragma unroll
  for (int k = 0; k < 8; ++k) {
    f32x4 o;
    o.x = r[4 * k + 0]; o.y = r[4 * k + 1]; o.z = r[4 * k + 2]; o.w = r[4 * k + 3];
    dst[k] = o;
  }
}

// ------------------------------------------- K2: warp + variance + contract
template <int T>
__device__ __forceinline__ void warp_accum(
    const char* __restrict__ refp,
    const char* const* tb,          // 4*T tap base pointers (128B per pixel)
    const float* tw,                // 4*T tap weights
    const float* __restrict__ wf,
    __hip_bfloat16* __restrict__ WV, int idx)
{
  f32x2 wv[14];
#pragma unroll
  for (int u = 0; u < 14; ++u) { wv[u].x = 0.f; wv[u].y = 0.f; }

#pragma unroll
  for (int k = 0; k < 8; ++k) {           // 8 chunks x 4 channels
    f32x4 vs = *(const f32x4*)(refp + k * 16);
    f32x4 vq;
    vq.x = vs.x * vs.x; vq.y = vs.y * vs.y; vq.z = vs.z * vs.z; vq.w = vs.w * vs.w;
#pragma unroll
    for (int v = 0; v < 4; ++v) {
      f32x4 val; val.x = 0.f; val.y = 0.f; val.z = 0.f; val.w = 0.f;
#pragma unroll
      for (int t = 0; t < T; ++t) {
        f32x4 f = *(const f32x4*)(tb[v * T + t] + k * 16);
        float w = tw[v * T + t];
        val.x += f.x * w; val.y += f.y * w; val.z += f.z * w; val.w += f.w * w;
      }
      vs.x += val.x; vs.y += val.y; vs.z += val.z; vs.w += val.w;
      vq.x += val.x * val.x; vq.y += val.y * val.y;
      vq.z += val.z * val.z; vq.w += val.w * val.w;
    }
    f32x4 var;
    var.x = vq.x * 0.2f - (vs.x * 0.2f) * (vs.x * 0.2f);
    var.y = vq.y * 0.2f - (vs.y * 0.2f) * (vs.y * 0.2f);
    var.z = vq.z * 0.2f - (vs.z * 0.2f) * (vs.z * 0.2f);
    var.w = vq.w * 0.2f - (vs.w * 0.2f) * (vs.w * 0.2f);
#pragma unroll
    for (int ch = 0; ch < 4; ++ch) {
      float vv = var[ch];
      const f32x2* wrow = (const f32x2*)(wf + (k * 4 + ch) * 28);
#pragma unroll
      for (int u = 0; u < 14; ++u) {
        wv[u].x += wrow[u].x * vv;
        wv[u].y += wrow[u].y * vv;
      }
    }
  }

#pragma unroll
  for (int u = 0; u < 14; ++u) {
    int t0 = 2 * u;
    WV[t0 * DHW + idx] = __float2bfloat16(wv[u].x);
    if (t0 + 1 < 27) WV[(t0 + 1) * DHW + idx] = __float2bfloat16(wv[u].y);
  }
}

__global__ __launch_bounds__(256) void k_warpvar(
    const float* __restrict__ featT,   // [5][HW][32]
    const float* __restrict__ depthv,  // [48]
    const float* __restrict__ M,       // [4][12]
    const float* __restrict__ wf,      // [32][28]
    __hip_bfloat16* __restrict__ WV)   // [27][DHW]
{
  int idx = blockIdx.x * 256 + threadIdx.x;
  int x = idx % NW;
  int t1 = idx / NW;
  int y = t1 % NH;
  int d = t1 / NH;
  float xf = (float)x, yf = (float)y;
  float df = depthv[d];

  const char* tb4[16];
  float tw4[16];
  bool all2 = true;
#pragma unroll
  for (int v = 0; v < 4; ++v) {
    const float* m = M + v * 12;
    float rx = m[0] * xf + m[1] * yf + m[2];
    float ry = m[3] * xf + m[4] * yf + m[5];
    float rz = m[6] * xf + m[7] * yf + m[8];
    float px = rx * df + m[9];
    float py = ry * df + m[10];
    float pz = rz * df + m[11];
    float gx = px / pz;
    float gy = py / pz;
    float x0 = floorf(gx), y0 = floorf(gy);
    float wx = gx - x0, wy = gy - y0;
    all2 = all2 && (wy == 0.f);
    float cxs[2] = {x0, x0 + 1.f}, cys[2] = {y0, y0 + 1.f};
    float wxs[2] = {1.f - wx, wx}, wys[2] = {1.f - wy, wy};
    const char* vbase = (const char*)featT + (size_t)(v + 1) * HW * (NC * 4);
#pragma unroll
    for (int cy = 0; cy < 2; ++cy)
#pragma unroll
      for (int cx = 0; cx < 2; ++cx) {
        float fx = cxs[cx], fy = cys[cy];
        bool valid = (fx >= 0.f) && (fx <= (float)(NW - 1)) &&
                     (fy >= 0.f) && (fy <= (float)(NH - 1));
        float fxc = fminf(fmaxf(fx, 0.f), (float)(NW - 1));
        float fyc = fminf(fmaxf(fy, 0.f), (float)(NH - 1));
        int xi = (int)fxc, yi = (int)fyc;
        tb4[v * 4 + cy * 2 + cx] = vbase + (size_t)(yi * NW + xi) * (NC * 4);
        tw4[v * 4 + cy * 2 + cx] = wxs[cx] * wys[cy] * (valid ? 1.f : 0.f);
      }
  }
  int pix = y * NW + x;
  const char* refp = (const char*)featT + (size_t)pix * (NC * 4);

  if (all2) {
    // wy == 0 for every view: the y0+1 corners carry weight 0 -> 2-tap lerp.
    const char* tb2[8];
    float tw2[8];
#pragma unroll
    for (int v = 0; v < 4; ++v) {
      tb2[v * 2 + 0] = tb4[v * 4 + 0]; tw2[v * 2 + 0] = tw4[v * 4 + 0];
      tb2[v * 2 + 1] = tb4[v * 4 + 1]; tw2[v * 2 + 1] = tw4[v * 4 + 1];
    }
    warp_accum<2>(refp, tb2, tw2, wf, WV, idx);
  } else {
    warp_accum<4>(refp, tb4, tw4, wf, WV, idx);
  }
}

// ------------------------------------------------- K3a: 27-tap gather (conv)
__global__ __launch_bounds__(256) void k_conv(const __hip_bfloat16* __restrict__ WV,
                                              float* __restrict__ pre) {
  int idx = blockIdx.x * 256 + threadIdx.x;
  int x = idx % NW;
  int t1 = idx / NW;
  int y = t1 % NH;
  int d = t1 / NH;
  float acc = 0.f;
#pragma unroll
  for (int dd = 0; dd < 3; ++dd) {
    int dp = d + dd - 1;
    bool dok = (dp >= 0) && (dp < ND);
    int dpc = min(max(dp, 0), ND - 1);
#pragma unroll
    for (int i = 0; i < 3; ++i) {
      int yp = y + i - 1;
      bool yok = (yp >= 0) && (yp < NH);
      int ypc = min(max(yp, 0), NH - 1);
#pragma unroll
      for (int j = 0; j < 3; ++j) {
        int xp = x + j - 1;
        bool xok = (xp >= 0) && (xp < NW);
        int xpc = min(max(xp, 0), NW - 1);
        int t = dd * 9 + i * 3 + j;
        float v = __bfloat162float(WV[t * DHW + dpc * HW + ypc * NW + xpc]);
        acc += (dok && yok && xok) ? v : 0.f;
      }
    }
  }
  pre[idx] = acc;
}

// ---------------------------------------- K3b: softmax over D + depth + conf
__global__ __launch_bounds__(256) void k_softmax(const float* __restrict__ pre,
                                                 const float* __restrict__ depthv,
                                                 float* __restrict__ depthf,
                                                 float* __restrict__ out_depth,
                                                 float* __restrict__ out_conf) {
  int p = blockIdx.x * 256 + threadIdx.x;
  float pr[ND];
  float m = -1e30f;
#pragma unroll
  for (int d = 0; d < ND; ++d) { pr[d] = pre[d * HW + p]; m = fmaxf(m, pr[d]); }
  float s = 0.f;
#pragma unroll
  for (int d = 0; d < ND; ++d) { pr[d] = expf(pr[d] - m); s += pr[d]; }
  float inv = 1.f / s;
  float dep = 0.f, ti = 0.f;
#pragma unroll
  for (int d = 0; d < ND; ++d) {
    float prob = pr[d] * inv;
    pr[d] = prob;
    dep += prob * depthv[d];
    ti += prob * (float)d;
  }
  int di = (int)ti;
  di = di < 0 ? 0 : (di > ND - 1 ? ND - 1 : di);
  float conf = 0.f;
#pragma unroll
  for (int d = 0; d < ND; ++d)
    conf += (d >= di - 1 && d <= di + 2) ? pr[d] : 0.f;
  depthf[p] = dep;
  out_depth[p] = dep;
  out_conf[p] = conf;
}

// -------------------------------------------------- K4: convex upsample (x8)
__global__ __launch_bounds__(256) void k_upsample(const float* __restrict__ mask,
                                                  const float* __restrict__ depthf,
                                                  float* __restrict__ out) {
  int idx = blockIdx.x * 256 + threadIdx.x;  // row-major over (1024, 1280)
  int fx = idx % (NW * 8);
  int fy = idx / (NW * 8);
  int x = fx >> 3, dx = fx & 7;
  int y = fy >> 3, dy = fy & 7;
  float mv[9];
  float mmax = -1e30f;
#pragma unroll
  for (int k = 0; k < 9; ++k) {
    mv[k] = mask[((k * 8 + dy) * 8 + dx) * HW + y * NW + x];
    mmax = fmaxf(mmax, mv[k]);
  }
  float s = 0.f;
#pragma unroll
  for (int k = 0; k < 9; ++k) { mv[k] = expf(mv[k] - mmax); s += mv[k]; }
  float acc = 0.f;
#pragma unroll
  for (int k = 0; k < 9; ++k) {
    int ky = y + k / 3 - 1;
    int kx = x + k % 3 - 1;
    bool ok = (ky >= 0) && (ky < NH) && (kx >= 0) && (kx < NW);
    int kyc = min(max(ky, 0), NH - 1);
    int kxc = min(max(kx, 0), NW - 1);
    float dv = depthf[kyc * NW + kxc];
    acc += mv[k] * (ok ? dv : 0.f);
  }
  out[idx] = acc / s;
}

// ---------------------------------------------------------------- launcher
extern "C" void kernel_launch(void* const* d_in, const int* in_sizes, int n_in,
                              void* d_out, int out_size, void* d_ws, size_t ws_size,
                              hipStream_t stream) {
  const float* feat   = (const float*)d_in[0];
  const float* proj   = (const float*)d_in[1];
  const float* depthv = (const float*)d_in[2];
  const float* mask   = (const float*)d_in[3];
  const float* wreg   = (const float*)d_in[4];

  char* ws = (char*)d_ws;
  float* M       = (float*)(ws + OFF_M);
  float* wf      = (float*)(ws + OFF_WF);
  float* depthf  = (float*)(ws + OFF_DEPTHF);
  float* featT   = (float*)(ws + OFF_FEATT);
  float* pre     = (float*)(ws + OFF_PRE);     // aliases featT (dead by then)
  __hip_bfloat16* WV = (__hip_bfloat16*)(ws + OFF_WV);

  float* out = (float*)d_out;
  float* out_depth = out + (NH * 8) * (NW * 8);
  float* out_conf  = out_depth + HW;

  k_setup<<<1, 64, 0, stream>>>(proj, wreg, M, wf);
  k_transpose<<<(NV * HW) / 256, 256, 0, stream>>>(feat, featT);
  k_warpvar<<<DHW / 256, 256, 0, stream>>>(featT, depthv, M, wf, WV);
  k_conv<<<DHW / 256, 256, 0, stream>>>(WV, pre);
  k_softmax<<<HW / 256, 256, 0, stream>>>(pre, depthv, depthf, out_depth, out_conf);
  k_upsample<<<(NH * 8 * NW * 8) / 256, 256, 0, stream>>>(mask, depthf, out);
}

// Round 2
// 330.864 us; speedup vs baseline: 1.4820x; 1.4820x over previous
//
#include <hip/hip_runtime.h>
#include <hip/hip_bf16.h>

// Effi_MVS: B=1, V=5, C=32, D=48, H=128, W=160, RATIO=8.
// Round 5: revert round-4's HWC transpose (uncoalesced: 64 lines/load, 153->356us).
// Keep CHW (coalesced) and cut VMEM instructions instead:
//   - 2-tap collapse: wy==0 or wy==1 detected per view/px (general fallback kept)
//   - each x-tap pair read as ONE dwordx2 + cndmask edge handling (branchless,
//     in-bounds incl. the absolute buffer-end corner via base shift delta)
//   - 2 pixels per thread: tap state + uniform wf reads + contraction amortized
// VMEM: 544/voxel -> 144/voxel. Predicted k_warpvar ~40us.

#define NV 5
#define NC 32
#define ND 48
#define NH 128
#define NW 160
#define HW (NH * NW)
#define DHW (ND * HW)

typedef __attribute__((ext_vector_type(2))) float f32x2;
typedef __attribute__((ext_vector_type(2), aligned(4))) float f32x2u;

// ws layout (bytes) — round-3 layout
#define OFF_M      0          // float M[4][12]
#define OFF_WF     256        // float wf[32][28]
#define OFF_DEPTHF 4096       // float depthf[20480]
#define OFF_PRE    86016      // float pre[48*128*160]
#define OFF_WV     4018176    // bf16 WV[27][48*128*160]
// total = 57,102,336 bytes

__device__ __forceinline__ uint32_t pack_bf16(float a, float b) {
  __hip_bfloat16 ba = __float2bfloat16(a), bb = __float2bfloat16(b);
  uint16_t ua, ub;
  __builtin_memcpy(&ua, &ba, 2);
  __builtin_memcpy(&ub, &bb, 2);
  return (uint32_t)ua | ((uint32_t)ub << 16);
}

// ---------------------------------------------------------------- K1: setup
__global__ void k_setup(const float* __restrict__ proj,
                        const float* __restrict__ wreg,
                        float* __restrict__ M, float* __restrict__ wf) {
  if (threadIdx.x != 0) return;
  double P[NV][2][4][4];
  for (int v = 0; v < NV; ++v)
    for (int m = 0; m < 2; ++m)
      for (int i = 0; i < 4; ++i)
        for (int j = 0; j < 4; ++j)
          P[v][m][i][j] = (double)proj[((v * 2 + m) * 4 + i) * 4 + j];
  double C[NV][4][4];
  for (int v = 0; v < NV; ++v) {
    for (int i = 0; i < 4; ++i)
      for (int j = 0; j < 4; ++j) C[v][i][j] = P[v][0][i][j];
    for (int i = 0; i < 3; ++i)
      for (int j = 0; j < 4; ++j) {
        double s = 0.0;
        for (int k = 0; k < 3; ++k) s += P[v][1][i][k] * P[v][0][k][j];
        C[v][i][j] = s;
      }
  }
  double a[4][8];
  for (int i = 0; i < 4; ++i)
    for (int j = 0; j < 4; ++j) { a[i][j] = C[0][i][j]; a[i][j + 4] = (i == j) ? 1.0 : 0.0; }
  for (int col = 0; col < 4; ++col) {
    int piv = col; double best = fabs(a[col][col]);
    for (int r = col + 1; r < 4; ++r) { double v = fabs(a[r][col]); if (v > best) { best = v; piv = r; } }
    if (piv != col)
      for (int j = 0; j < 8; ++j) { double t = a[col][j]; a[col][j] = a[piv][j]; a[piv][j] = t; }
    double pv = a[col][col];
    for (int j = 0; j < 8; ++j) a[col][j] /= pv;
    for (int r = 0; r < 4; ++r) if (r != col) {
      double f = a[r][col];
      for (int j = 0; j < 8; ++j) a[r][j] -= f * a[col][j];
    }
  }
  double inv[4][4];
  for (int i = 0; i < 4; ++i)
    for (int j = 0; j < 4; ++j) inv[i][j] = a[i][j + 4];
  for (int v = 1; v < NV; ++v) {
    float* m = M + (v - 1) * 12;
    for (int i = 0; i < 3; ++i) {
      double r[4] = {0, 0, 0, 0};
      for (int k = 0; k < 4; ++k) {
        double cv = C[v][i][k];
        for (int j = 0; j < 4; ++j) r[j] += cv * inv[k][j];
      }
      m[i * 3 + 0] = (float)r[0]; m[i * 3 + 1] = (float)r[1]; m[i * 3 + 2] = (float)r[2];
      m[9 + i] = (float)r[3];
    }
  }
  for (int c = 0; c < NC; ++c) {
    for (int t = 0; t < 27; ++t) wf[c * 28 + t] = wreg[c * 27 + t];
    wf[c * 28 + 27] = 0.f;
  }
}

// ------------------------------------------- K2: warp + variance + contract
__global__ __launch_bounds__(256) void k_warpvar(
    const float* __restrict__ feat,    // [5][32][128][160]
    const float* __restrict__ depthv,  // [48]
    const float* __restrict__ M,       // [4][12]
    const float* __restrict__ wf,      // [32][28]
    uint32_t* __restrict__ WV2)        // [27][DHW/2] bf16 pairs
{
  int t = blockIdx.x * 256 + threadIdx.x;   // [0, DHW/2)
  int idx0 = t * 2;
  int x = idx0 % NW;                        // even; px pair same row & depth
  int t1 = idx0 / NW;
  int y = t1 % NH;
  int d = t1 / NH;
  int pix = y * NW + x;
  float yf = (float)y;
  float df = depthv[d];

  // per-view, per-px 2-tap state
  int offA[4], offB[4];
  int sA[4], sB[4], dA[4], dB[4];
  float w0A[4], w1A[4], w0B[4], w1B[4];
  bool any4 = false;

#pragma unroll
  for (int v = 0; v < 4; ++v) {
    const float* m = M + v * 12;
    int offs[2], ss[2], dds[2];
    float w0s[2], w1s[2];
#pragma unroll
    for (int j = 0; j < 2; ++j) {
      float xf = (float)(x + j);
      float rx = m[0] * xf + m[1] * yf + m[2];
      float ry = m[3] * xf + m[4] * yf + m[5];
      float rz = m[6] * xf + m[7] * yf + m[8];
      float px = rx * df + m[9];
      float py = ry * df + m[10];
      float pz = rz * df + m[11];
      float gx = px / pz;
      float gy = py / pz;
      float y0 = floorf(gy);
      float wy = gy - y0;
      bool two = (wy == 0.f) || (wy == 1.f);
      any4 = any4 || !two;
      float rowf = (wy == 0.f) ? y0 : (y0 + 1.f);   // the single y-row kept
      float x0 = floorf(gx);
      float wx = gx - x0;
      bool yok  = (rowf >= 0.f) && (rowf <= (float)(NH - 1));
      bool x0ok = (x0 >= 0.f) && (x0 <= (float)(NW - 1)) && yok;
      bool x1ok = (x0 + 1.f >= 0.f) && (x0 + 1.f <= (float)(NW - 1)) && yok;
      float rc = fminf(fmaxf(rowf, 0.f), (float)(NH - 1));
      float xc = fminf(fmaxf(x0, 0.f), (float)(NW - 1));
      int xi = (int)xc;
      int off = (int)rc * NW + xi;
      int s  = (xi <= NW - 2) ? 1 : 0;        // tap1 exists in-row
      int dd = (off == HW - 1) ? 1 : 0;       // absolute plane-end: shift base
      offs[j] = off - dd;
      ss[j] = s; dds[j] = dd;
      w0s[j] = (1.f - wx) * (x0ok ? 1.f : 0.f);
      w1s[j] = wx * (x1ok ? 1.f : 0.f);
    }
    offA[v] = offs[0]; offB[v] = offs[1];
    sA[v] = ss[0]; sB[v] = ss[1];
    dA[v] = dds[0]; dB[v] = dds[1];
    w0A[v] = w0s[0]; w1A[v] = w1s[0];
    w0B[v] = w0s[1]; w1B[v] = w1s[1];
  }

  if (any4) {
    // ------- general 4-tap fallback (round-3 semantics), both px serially
    f32x2 acc[27];
#pragma unroll
    for (int u = 0; u < 27; ++u) { acc[u].x = 0.f; acc[u].y = 0.f; }
#pragma unroll
    for (int j = 0; j < 2; ++j) {
      float xf = (float)(x + j);
      int cidx[16]; float cw[16];
#pragma unroll
      for (int v = 0; v < 4; ++v) {
        const float* m = M + v * 12;
        float rx = m[0] * xf + m[1] * yf + m[2];
        float ry = m[3] * xf + m[4] * yf + m[5];
        float rz = m[6] * xf + m[7] * yf + m[8];
        float px = rx * df + m[9];
        float py = ry * df + m[10];
        float pz = rz * df + m[11];
        float gx = px / pz;
        float gy = py / pz;
        float x0 = floorf(gx), y0 = floorf(gy);
        float wx = gx - x0, wy = gy - y0;
        float cxs[2] = {x0, x0 + 1.f}, cys[2] = {y0, y0 + 1.f};
        float wxs[2] = {1.f - wx, wx}, wys[2] = {1.f - wy, wy};
#pragma unroll
        for (int cy = 0; cy < 2; ++cy)
#pragma unroll
          for (int cx = 0; cx < 2; ++cx) {
            float fx = cxs[cx], fy = cys[cy];
            bool valid = (fx >= 0.f) && (fx <= (float)(NW - 1)) &&
                         (fy >= 0.f) && (fy <= (float)(NH - 1));
            float fxc = fminf(fmaxf(fx, 0.f), (float)(NW - 1));
            float fyc = fminf(fmaxf(fy, 0.f), (float)(NH - 1));
            int xi2 = (int)fxc, yi2 = (int)fyc;
            cidx[v * 4 + cy * 2 + cx] = yi2 * NW + xi2;
            cw[v * 4 + cy * 2 + cx] = wxs[cx] * wys[cy] * (valid ? 1.f : 0.f);
          }
      }
      int pj = pix + j;
#pragma unroll 4
      for (int c = 0; c < NC; ++c) {
        float f0 = feat[c * HW + pj];
        float vsS = f0, vqS = f0 * f0;
#pragma unroll
        for (int v = 0; v < 4; ++v) {
          const float* fv = feat + ((v + 1) * NC + c) * HW;
          float val = cw[v * 4 + 0] * fv[cidx[v * 4 + 0]]
                    + cw[v * 4 + 1] * fv[cidx[v * 4 + 1]]
                    + cw[v * 4 + 2] * fv[cidx[v * 4 + 2]]
                    + cw[v * 4 + 3] * fv[cidx[v * 4 + 3]];
          vsS += val;
          vqS += val * val;
        }
        float var = vqS * 0.2f - (vsS * 0.2f) * (vsS * 0.2f);
        const float* wrow = wf + c * 28;
#pragma unroll
        for (int u = 0; u < 27; ++u) {
          if (j == 0) acc[u].x += wrow[u] * var;
          else        acc[u].y += wrow[u] * var;
        }
      }
    }
#pragma unroll
    for (int u = 0; u < 27; ++u)
      WV2[(size_t)u * (DHW / 2) + t] = pack_bf16(acc[u].x, acc[u].y);
    return;
  }

  // ------------------------------- fast branchless 2-tap path (both px)
  f32x2 wv2[27];
#pragma unroll
  for (int u = 0; u < 27; ++u) { wv2[u].x = 0.f; wv2[u].y = 0.f; }

#pragma unroll 4
  for (int c = 0; c < NC; ++c) {
    const float* fc = feat + c * HW;
    f32x2 r2 = *(const f32x2*)(fc + pix);     // pix even -> 8B aligned
    f32x2 vs = r2;
    f32x2 vq = r2 * r2;
#pragma unroll
    for (int v = 0; v < 4; ++v) {
      const float* fv = feat + ((v + 1) * NC + c) * HW;
      f32x2u ea = *(const f32x2u*)(fv + offA[v]);
      f32x2u eb = *(const f32x2u*)(fv + offB[v]);
      float a0 = dA[v] ? ea.y : ea.x;          // base-shift undo at plane end
      float a1 = sA[v] ? ea.y : a0;            // tap1 clamps to tap0 at x=159
      float b0 = dB[v] ? eb.y : eb.x;
      float b1 = sB[v] ? eb.y : b0;
      float vx = w0A[v] * a0 + w1A[v] * a1;
      float vy = w0B[v] * b0 + w1B[v] * b1;
      vs.x += vx; vs.y += vy;
      vq.x += vx * vx; vq.y += vy * vy;
    }
    f32x2 var;
    var.x = vq.x * 0.2f - (vs.x * 0.2f) * (vs.x * 0.2f);
    var.y = vq.y * 0.2f - (vs.y * 0.2f) * (vs.y * 0.2f);
    const float* wrow = wf + c * 28;           // wave-uniform -> SMEM
#pragma unroll
    for (int u = 0; u < 27; ++u) {
      float w = wrow[u];
      wv2[u].x += w * var.x;
      wv2[u].y += w * var.y;
    }
  }

#pragma unroll
  for (int u = 0; u < 27; ++u)
    WV2[(size_t)u * (DHW / 2) + t] = pack_bf16(wv2[u].x, wv2[u].y);
}

// ------------------------------------------------- K3a: 27-tap gather (conv)
__global__ __launch_bounds__(256) void k_conv(const __hip_bfloat16* __restrict__ WV,
                                              float* __restrict__ pre) {
  int idx = blockIdx.x * 256 + threadIdx.x;
  int x = idx % NW;
  int t1 = idx / NW;
  int y = t1 % NH;
  int d = t1 / NH;
  float acc = 0.f;
#pragma unroll
  for (int dd = 0; dd < 3; ++dd) {
    int dp = d + dd - 1;
    bool dok = (dp >= 0) && (dp < ND);
    int dpc = min(max(dp, 0), ND - 1);
#pragma unroll
    for (int i = 0; i < 3; ++i) {
      int yp = y + i - 1;
      bool yok = (yp >= 0) && (yp < NH);
      int ypc = min(max(yp, 0), NH - 1);
#pragma unroll
      for (int j = 0; j < 3; ++j) {
        int xp = x + j - 1;
        bool xok = (xp >= 0) && (xp < NW);
        int xpc = min(max(xp, 0), NW - 1);
        int t = dd * 9 + i * 3 + j;
        float v = __bfloat162float(WV[t * DHW + dpc * HW + ypc * NW + xpc]);
        acc += (dok && yok && xok) ? v : 0.f;
      }
    }
  }
  pre[idx] = acc;
}

// ---------------------------------------- K3b: softmax over D + depth + conf
__global__ __launch_bounds__(256) void k_softmax(const float* __restrict__ pre,
                                                 const float* __restrict__ depthv,
                                                 float* __restrict__ depthf,
                                                 float* __restrict__ out_depth,
                                                 float* __restrict__ out_conf) {
  int p = blockIdx.x * 256 + threadIdx.x;
  float pr[ND];
  float m = -1e30f;
#pragma unroll
  for (int d = 0; d < ND; ++d) { pr[d] = pre[d * HW + p]; m = fmaxf(m, pr[d]); }
  float s = 0.f;
#pragma unroll
  for (int d = 0; d < ND; ++d) { pr[d] = expf(pr[d] - m); s += pr[d]; }
  float inv = 1.f / s;
  float dep = 0.f, ti = 0.f;
#pragma unroll
  for (int d = 0; d < ND; ++d) {
    float prob = pr[d] * inv;
    pr[d] = prob;
    dep += prob * depthv[d];
    ti += prob * (float)d;
  }
  int di = (int)ti;
  di = di < 0 ? 0 : (di > ND - 1 ? ND - 1 : di);
  float conf = 0.f;
#pragma unroll
  for (int d = 0; d < ND; ++d)
    conf += (d >= di - 1 && d <= di + 2) ? pr[d] : 0.f;
  depthf[p] = dep;
  out_depth[p] = dep;
  out_conf[p] = conf;
}

// -------------------------------------------------- K4: convex upsample (x8)
__global__ __launch_bounds__(256) void k_upsample(const float* __restrict__ mask,
                                                  const float* __restrict__ depthf,
                                                  float* __restrict__ out) {
  int idx = blockIdx.x * 256 + threadIdx.x;  // row-major over (1024, 1280)
  int fx = idx % (NW * 8);
  int fy = idx / (NW * 8);
  int x = fx >> 3, dx = fx & 7;
  int y = fy >> 3, dy = fy & 7;
  float mv[9];
  float mmax = -1e30f;
#pragma unroll
  for (int k = 0; k < 9; ++k) {
    mv[k] = mask[((k * 8 + dy) * 8 + dx) * HW + y * NW + x];
    mmax = fmaxf(mmax, mv[k]);
  }
  float s = 0.f;
#pragma unroll
  for (int k = 0; k < 9; ++k) { mv[k] = expf(mv[k] - mmax); s += mv[k]; }
  float acc = 0.f;
#pragma unroll
  for (int k = 0; k < 9; ++k) {
    int ky = y + k / 3 - 1;
    int kx = x + k % 3 - 1;
    bool ok = (ky >= 0) && (ky < NH) && (kx >= 0) && (kx < NW);
    int kyc = min(max(ky, 0), NH - 1);
    int kxc = min(max(kx, 0), NW - 1);
    float dv = depthf[kyc * NW + kxc];
    acc += mv[k] * (ok ? dv : 0.f);
  }
  out[idx] = acc / s;
}

// ---------------------------------------------------------------- launcher
extern "C" void kernel_launch(void* const* d_in, const int* in_sizes, int n_in,
                              void* d_out, int out_size, void* d_ws, size_t ws_size,
                              hipStream_t stream) {
  const float* feat   = (const float*)d_in[0];
  const float* proj   = (const float*)d_in[1];
  const float* depthv = (const float*)d_in[2];
  const float* mask   = (const float*)d_in[3];
  const float* wreg   = (const float*)d_in[4];

  char* ws = (char*)d_ws;
  float* M       = (float*)(ws + OFF_M);
  float* wf      = (float*)(ws + OFF_WF);
  float* depthf  = (float*)(ws + OFF_DEPTHF);
  float* pre     = (float*)(ws + OFF_PRE);
  uint32_t* WV2  = (uint32_t*)(ws + OFF_WV);
  const __hip_bfloat16* WV = (const __hip_bfloat16*)(ws + OFF_WV);

  float* out = (float*)d_out;
  float* out_depth = out + (NH * 8) * (NW * 8);
  float* out_conf  = out_depth + HW;

  k_setup<<<1, 64, 0, stream>>>(proj, wreg, M, wf);
  k_warpvar<<<(DHW / 2) / 256, 256, 0, stream>>>(feat, depthv, M, wf, WV2);
  k_conv<<<DHW / 256, 256, 0, stream>>>(WV, pre);
  k_softmax<<<HW / 256, 256, 0, stream>>>(pre, depthv, depthf, out_depth, out_conf);
  k_upsample<<<(NH * 8 * NW * 8) / 256, 256, 0, stream>>>(mask, depthf, out);
}

// Round 3
// 241.326 us; speedup vs baseline: 2.0319x; 1.3710x over previous
//
#include <hip/hip_runtime.h>
#include <hip/hip_bf16.h>

// Effi_MVS: B=1, V=5, C=32, D=48, H=128, W=160, RATIO=8.
// Round 6: R5 post-mortem — halving waves (2 vox/thread) made the kernel
// latency-bound (VALU 28%, occ 12%). Revert to R3's proven TLP regime
// (1 voxel/thread, 15360 waves, full-unrolled channel loop) and keep only
// the load-count win, reformulated select-free:
//   - 2-tap gather: one dwordx2 per view per channel (5 VMEM/ch vs 17)
//   - edge handling folded into weights: val = A*e.x + B*e.y (A,B computed
//     once in prologue; covers clamp, plane-end base shift, validity, and
//     fixes R5's latent x0==-1 wrong-tap bug)
//   - compact rolled-c fallback (4-tap general path; v/u unrolled so all
//     arrays stay register-indexed)
// k_upsample: 8 outputs (dx) per thread -> every mask load lane-coalesced
// (old: dx fastest across lanes at stride HW => ~8 lines per load instr).

#define NV 5
#define NC 32
#define ND 48
#define NH 128
#define NW 160
#define HW (NH * NW)
#define DHW (ND * HW)

typedef __attribute__((ext_vector_type(2))) float f32x2;
typedef __attribute__((ext_vector_type(4))) float f32x4;
typedef __attribute__((ext_vector_type(2), aligned(4))) float f32x2u;

// ws layout (bytes)
#define OFF_M      0          // float M[4][12]
#define OFF_WF     256        // float wf[32][28]
#define OFF_DEPTHF 4096       // float depthf[20480]
#define OFF_PRE    86016      // float pre[48*128*160]
#define OFF_WV     4018176    // bf16 WV[27][48*128*160]
// total = 57,102,336 bytes

// ---------------------------------------------------------------- K1: setup
__global__ void k_setup(const float* __restrict__ proj,
                        const float* __restrict__ wreg,
                        float* __restrict__ M, float* __restrict__ wf) {
  if (threadIdx.x != 0) return;
  double P[NV][2][4][4];
  for (int v = 0; v < NV; ++v)
    for (int m = 0; m < 2; ++m)
      for (int i = 0; i < 4; ++i)
        for (int j = 0; j < 4; ++j)
          P[v][m][i][j] = (double)proj[((v * 2 + m) * 4 + i) * 4 + j];
  double C[NV][4][4];
  for (int v = 0; v < NV; ++v) {
    for (int i = 0; i < 4; ++i)
      for (int j = 0; j < 4; ++j) C[v][i][j] = P[v][0][i][j];
    for (int i = 0; i < 3; ++i)
      for (int j = 0; j < 4; ++j) {
        double s = 0.0;
        for (int k = 0; k < 3; ++k) s += P[v][1][i][k] * P[v][0][k][j];
        C[v][i][j] = s;
      }
  }
  double a[4][8];
  for (int i = 0; i < 4; ++i)
    for (int j = 0; j < 4; ++j) { a[i][j] = C[0][i][j]; a[i][j + 4] = (i == j) ? 1.0 : 0.0; }
  for (int col = 0; col < 4; ++col) {
    int piv = col; double best = fabs(a[col][col]);
    for (int r = col + 1; r < 4; ++r) { double v = fabs(a[r][col]); if (v > best) { best = v; piv = r; } }
    if (piv != col)
      for (int j = 0; j < 8; ++j) { double t = a[col][j]; a[col][j] = a[piv][j]; a[piv][j] = t; }
    double pv = a[col][col];
    for (int j = 0; j < 8; ++j) a[col][j] /= pv;
    for (int r = 0; r < 4; ++r) if (r != col) {
      double f = a[r][col];
      for (int j = 0; j < 8; ++j) a[r][j] -= f * a[col][j];
    }
  }
  double inv[4][4];
  for (int i = 0; i < 4; ++i)
    for (int j = 0; j < 4; ++j) inv[i][j] = a[i][j + 4];
  for (int v = 1; v < NV; ++v) {
    float* m = M + (v - 1) * 12;
    for (int i = 0; i < 3; ++i) {
      double r[4] = {0, 0, 0, 0};
      for (int k = 0; k < 4; ++k) {
        double cv = C[v][i][k];
        for (int j = 0; j < 4; ++j) r[j] += cv * inv[k][j];
      }
      m[i * 3 + 0] = (float)r[0]; m[i * 3 + 1] = (float)r[1]; m[i * 3 + 2] = (float)r[2];
      m[9 + i] = (float)r[3];
    }
  }
  for (int c = 0; c < NC; ++c) {
    for (int t = 0; t < 27; ++t) wf[c * 28 + t] = wreg[c * 27 + t];
    wf[c * 28 + 27] = 0.f;
  }
}

// ------------------------------------------- K2: warp + variance + contract
__global__ __launch_bounds__(256) void k_warpvar(
    const float* __restrict__ feat,    // [5][32][128][160]
    const float* __restrict__ depthv,  // [48]
    const float* __restrict__ M,       // [4][12]
    const float* __restrict__ wf,      // [32][28]
    __hip_bfloat16* __restrict__ WV)   // [27][DHW]
{
  int idx = blockIdx.x * 256 + threadIdx.x;   // [0, DHW)
  int x = idx % NW;
  int t1 = idx / NW;
  int y = t1 % NH;
  int d = t1 / NH;
  int pix = y * NW + x;
  float xf = (float)x, yf = (float)y;
  float df = depthv[d];

  int   off[4];
  float wA[4], wB[4];
  bool any4 = false;

#pragma unroll
  for (int v = 0; v < 4; ++v) {
    const float* m = M + v * 12;
    float rx = m[0] * xf + m[1] * yf + m[2];
    float ry = m[3] * xf + m[4] * yf + m[5];
    float rz = m[6] * xf + m[7] * yf + m[8];
    float px = rx * df + m[9];
    float py = ry * df + m[10];
    float pz = rz * df + m[11];
    float gx = px / pz;
    float gy = py / pz;
    float y0 = floorf(gy);
    float wy = gy - y0;
    bool two = (wy == 0.f) || (wy == 1.f);
    any4 = any4 || !two;
    float rowf = (wy == 0.f) ? y0 : (y0 + 1.f);  // single surviving y-row
    float x0 = floorf(gx);
    float wx = gx - x0;
    bool yok  = (rowf >= 0.f) && (rowf <= (float)(NH - 1));
    bool x0ok = (x0 >= 0.f) && (x0 <= (float)(NW - 1)) && yok;
    bool x1ok = (x0 + 1.f >= 0.f) && (x0 + 1.f <= (float)(NW - 1)) && yok;
    float rc = fminf(fmaxf(rowf, 0.f), (float)(NH - 1));
    float xc = fminf(fmaxf(x0, 0.f), (float)(NW - 1));
    int xi = (int)xc;
    int o = (int)rc * NW + xi;
    bool ddv = (o == HW - 1);          // absolute plane end: shift base by 1
    bool sv  = (x0 >= 0.f) && (xi <= NW - 2);  // e.y is a distinct valid tap1
    o -= ddv ? 1 : 0;
    float w0 = (1.f - wx) * (x0ok ? 1.f : 0.f);
    float w1 = wx * (x1ok ? 1.f : 0.f);
    float wsum = w0 + w1;
    // val = wA*e.x + wB*e.y  encodes all cases select-free:
    //  ddv: both taps sit at e.y (base shifted)  -> A=0,     B=w0+w1
    //  sv : e.x=tap0, e.y=tap1                   -> A=w0,    B=w1
    //  else (clamped: both taps same element e.x)-> A=w0+w1, B=0
    wA[v] = ddv ? 0.f : (sv ? w0 : wsum);
    wB[v] = ddv ? wsum : (sv ? w1 : 0.f);
    off[v] = o;
  }

  f32x2 wv[14];
#pragma unroll
  for (int u = 0; u < 14; ++u) { wv[u].x = 0.f; wv[u].y = 0.f; }

  if (__builtin_expect(any4, 0)) {
    // ---------- general 4-tap fallback (cold). v/u unrolled, c rolled.
    int cidx[16]; float cw[16];
#pragma unroll
    for (int v = 0; v < 4; ++v) {
      const float* m = M + v * 12;
      float rx = m[0] * xf + m[1] * yf + m[2];
      float ry = m[3] * xf + m[4] * yf + m[5];
      float rz = m[6] * xf + m[7] * yf + m[8];
      float px = rx * df + m[9];
      float py = ry * df + m[10];
      float pz = rz * df + m[11];
      float gx = px / pz;
      float gy = py / pz;
      float x0 = floorf(gx), y0 = floorf(gy);
      float wx = gx - x0, wy = gy - y0;
      float cxs[2] = {x0, x0 + 1.f}, cys[2] = {y0, y0 + 1.f};
      float wxs[2] = {1.f - wx, wx}, wys[2] = {1.f - wy, wy};
#pragma unroll
      for (int cy = 0; cy < 2; ++cy)
#pragma unroll
        for (int cx = 0; cx < 2; ++cx) {
          float fx = cxs[cx], fy = cys[cy];
          bool valid = (fx >= 0.f) && (fx <= (float)(NW - 1)) &&
                       (fy >= 0.f) && (fy <= (float)(NH - 1));
          float fxc = fminf(fmaxf(fx, 0.f), (float)(NW - 1));
          float fyc = fminf(fmaxf(fy, 0.f), (float)(NH - 1));
          int xi2 = (int)fxc, yi2 = (int)fyc;
          cidx[v * 4 + cy * 2 + cx] = yi2 * NW + xi2;
          cw[v * 4 + cy * 2 + cx] = wxs[cx] * wys[cy] * (valid ? 1.f : 0.f);
        }
    }
    for (int c = 0; c < NC; ++c) {   // rolled: cold path stays small
      float f0 = feat[c * HW + pix];
      float vs = f0, vq = f0 * f0;
#pragma unroll
      for (int v = 0; v < 4; ++v) {
        const float* fv = feat + ((v + 1) * NC + c) * HW;
        float val = cw[v * 4 + 0] * fv[cidx[v * 4 + 0]]
                  + cw[v * 4 + 1] * fv[cidx[v * 4 + 1]]
                  + cw[v * 4 + 2] * fv[cidx[v * 4 + 2]]
                  + cw[v * 4 + 3] * fv[cidx[v * 4 + 3]];
        vs += val;
        vq += val * val;
      }
      float var = vq * 0.2f - (vs * 0.2f) * (vs * 0.2f);
      const f32x2* wrow = (const f32x2*)(wf + c * 28);
      f32x2 vv; vv.x = var; vv.y = var;
#pragma unroll
      for (int u = 0; u < 14; ++u) wv[u] += wrow[u] * vv;
    }
  } else {
    // ---------- hot 2-tap path: 5 VMEM + ~36 VALU per channel
#pragma unroll
    for (int c = 0; c < NC; ++c) {
      float f0 = feat[c * HW + pix];
      float vs = f0, vq = f0 * f0;
#pragma unroll
      for (int v = 0; v < 4; ++v) {
        const float* fv = feat + ((v + 1) * NC + c) * HW;
        f32x2u e = *(const f32x2u*)(fv + off[v]);
        float val = wA[v] * e.x + wB[v] * e.y;
        vs += val;
        vq += val * val;
      }
      float var = vq * 0.2f - (vs * 0.2f) * (vs * 0.2f);
      const f32x2* wrow = (const f32x2*)(wf + c * 28);
      f32x2 vv; vv.x = var; vv.y = var;
#pragma unroll
      for (int u = 0; u < 14; ++u) wv[u] += wrow[u] * vv;
    }
  }

#pragma unroll
  for (int u = 0; u < 14; ++u) {
    int t0 = 2 * u;
    WV[t0 * DHW + idx] = __float2bfloat16(wv[u].x);
    if (t0 + 1 < 27) WV[(t0 + 1) * DHW + idx] = __float2bfloat16(wv[u].y);
  }
}

// ------------------------------------------------- K3a: 27-tap gather (conv)
__global__ __launch_bounds__(256) void k_conv(const __hip_bfloat16* __restrict__ WV,
                                              float* __restrict__ pre) {
  int idx = blockIdx.x * 256 + threadIdx.x;
  int x = idx % NW;
  int t1 = idx / NW;
  int y = t1 % NH;
  int d = t1 / NH;
  float acc = 0.f;
#pragma unroll
  for (int dd = 0; dd < 3; ++dd) {
    int dp = d + dd - 1;
    bool dok = (dp >= 0) && (dp < ND);
    int dpc = min(max(dp, 0), ND - 1);
#pragma unroll
    for (int i = 0; i < 3; ++i) {
      int yp = y + i - 1;
      bool yok = (yp >= 0) && (yp < NH);
      int ypc = min(max(yp, 0), NH - 1);
#pragma unroll
      for (int j = 0; j < 3; ++j) {
        int xp = x + j - 1;
        bool xok = (xp >= 0) && (xp < NW);
        int xpc = min(max(xp, 0), NW - 1);
        int t = dd * 9 + i * 3 + j;
        float v = __bfloat162float(WV[t * DHW + dpc * HW + ypc * NW + xpc]);
        acc += (dok && yok && xok) ? v : 0.f;
      }
    }
  }
  pre[idx] = acc;
}

// ---------------------------------------- K3b: softmax over D + depth + conf
__global__ __launch_bounds__(256) void k_softmax(const float* __restrict__ pre,
                                                 const float* __restrict__ depthv,
                                                 float* __restrict__ depthf,
                                                 float* __restrict__ out_depth,
                                                 float* __restrict__ out_conf) {
  int p = blockIdx.x * 256 + threadIdx.x;
  float pr[ND];
  float m = -1e30f;
#pragma unroll
  for (int d = 0; d < ND; ++d) { pr[d] = pre[d * HW + p]; m = fmaxf(m, pr[d]); }
  float s = 0.f;
#pragma unroll
  for (int d = 0; d < ND; ++d) { pr[d] = expf(pr[d] - m); s += pr[d]; }
  float inv = 1.f / s;
  float dep = 0.f, ti = 0.f;
#pragma unroll
  for (int d = 0; d < ND; ++d) {
    float prob = pr[d] * inv;
    pr[d] = prob;
    dep += prob * depthv[d];
    ti += prob * (float)d;
  }
  int di = (int)ti;
  di = di < 0 ? 0 : (di > ND - 1 ? ND - 1 : di);
  float conf = 0.f;
#pragma unroll
  for (int d = 0; d < ND; ++d)
    conf += (d >= di - 1 && d <= di + 2) ? pr[d] : 0.f;
  depthf[p] = dep;
  out_depth[p] = dep;
  out_conf[p] = conf;
}

// -------------------------------------------------- K4: convex upsample (x8)
// 8 outputs (dx 0..7) per thread: all mask loads lane-coalesced (pix varies
// across lanes, plane index uniform); depth taps shared across the 8 dx.
__global__ __launch_bounds__(256) void k_upsample(const float* __restrict__ mask,
                                                  const float* __restrict__ depthf,
                                                  float* __restrict__ out) {
  int idx = blockIdx.x * 256 + threadIdx.x;  // [0, HW*8)
  int x = idx % NW;
  int r = idx / NW;
  int y = r % NH;
  int dy = r / NH;                           // 0..7
  int pix = y * NW + x;

  float dv[9];
#pragma unroll
  for (int k = 0; k < 9; ++k) {
    int ky = y + k / 3 - 1;
    int kx = x + k % 3 - 1;
    bool ok = (ky >= 0) && (ky < NH) && (kx >= 0) && (kx < NW);
    int kyc = min(max(ky, 0), NH - 1);
    int kxc = min(max(kx, 0), NW - 1);
    float t = depthf[kyc * NW + kxc];
    dv[k] = ok ? t : 0.f;
  }

  float res[8];
#pragma unroll
  for (int dx = 0; dx < 8; ++dx) {
    float mv[9];
    float mmax = -1e30f;
#pragma unroll
    for (int k = 0; k < 9; ++k) {
      mv[k] = mask[(size_t)(k * 64 + dy * 8 + dx) * HW + pix];
      mmax = fmaxf(mmax, mv[k]);
    }
    float s = 0.f, acc = 0.f;
#pragma unroll
    for (int k = 0; k < 9; ++k) {
      float e = expf(mv[k] - mmax);
      s += e;
      acc += e * dv[k];
    }
    res[dx] = acc / s;
  }

  float* op = out + (size_t)(y * 8 + dy) * (NW * 8) + x * 8;
  f32x4 lo, hi;
  lo.x = res[0]; lo.y = res[1]; lo.z = res[2]; lo.w = res[3];
  hi.x = res[4]; hi.y = res[5]; hi.z = res[6]; hi.w = res[7];
  *(f32x4*)op = lo;
  *(f32x4*)(op + 4) = hi;
}

// ---------------------------------------------------------------- launcher
extern "C" void kernel_launch(void* const* d_in, const int* in_sizes, int n_in,
                              void* d_out, int out_size, void* d_ws, size_t ws_size,
                              hipStream_t stream) {
  const float* feat   = (const float*)d_in[0];
  const float* proj   = (const float*)d_in[1];
  const float* depthv = (const float*)d_in[2];
  const float* mask   = (const float*)d_in[3];
  const float* wreg   = (const float*)d_in[4];

  char* ws = (char*)d_ws;
  float* M       = (float*)(ws + OFF_M);
  float* wf      = (float*)(ws + OFF_WF);
  float* depthf  = (float*)(ws + OFF_DEPTHF);
  float* pre     = (float*)(ws + OFF_PRE);
  __hip_bfloat16* WV = (__hip_bfloat16*)(ws + OFF_WV);

  float* out = (float*)d_out;
  float* out_depth = out + (NH * 8) * (NW * 8);
  float* out_conf  = out_depth + HW;

  k_setup<<<1, 64, 0, stream>>>(proj, wreg, M, wf);
  k_warpvar<<<DHW / 256, 256, 0, stream>>>(feat, depthv, M, wf, WV);
  k_conv<<<DHW / 256, 256, 0, stream>>>(WV, pre);
  k_softmax<<<HW / 256, 256, 0, stream>>>(pre, depthv, depthf, out_depth, out_conf);
  k_upsample<<<(NH * 8 * NW * 8 / 8) / 256, 256, 0, stream>>>(mask, depthf, out);
}